// Round 5
// baseline (283.223 us; speedup 1.0000x reference)
//
#include <hip/hip_runtime.h>
#include <cstdint>

typedef __bf16 bf16x8 __attribute__((ext_vector_type(8)));
typedef float floatx4 __attribute__((ext_vector_type(4)));

// M = 4096 rows, C(K) = 256. GEMM block tile 128x128, K-slab 64.
// Staged layout: Xs[rb(32)][s(4)][kk(2)][rowhi(8)][quad(4)][rowlo(16)][8 bf16]
// = the exact LDS image for lane-linear global_load_lds staging and
// conflict-free lane-linear ds_read_b128 fragment reads.

#define OFF_X     (0u)
#define OFF_Y     (2u*1024*1024)
#define OFF_PMAX  (4u*1024*1024)   // [row(4096)][g(64)]
#define OFF_PSUM  (5u*1024*1024)
#define OFF_DIAG  (6u*1024*1024)
#define OFF_CTR   (6u*1024*1024 + 65536u)   // 2 x u32 barrier counters

#define AS1C(p) ((const __attribute__((address_space(1))) void*)(const void*)(p))
#define AS3(p)  ((__attribute__((address_space(3))) void*)(void*)(p))

// Manual grid barrier: graph-capture-proof (plain atomics). Requires all
// blocks co-resident: 512 blocks, LDS 32KB -> 5/CU, launch_bounds(256,2)
// caps VGPR<=256 -> >=2 blocks/CU by resources on 256 CUs.
__device__ __forceinline__ void grid_barrier(unsigned* ctr, unsigned nblk) {
  __threadfence();          // release: flush this block's writes device-wide
  __syncthreads();
  if (threadIdx.x == 0) {
    atomicAdd(ctr, 1u);
    while (atomicAdd(ctr, 0u) < nblk) __builtin_amdgcn_s_sleep(2);
  }
  __syncthreads();
  __threadfence();          // acquire: invalidate stale L1/L2 before reads
}

__global__ __launch_bounds__(256, 2) void dpc_fused(
    const float* __restrict__ pred, const float* __restrict__ gt,
    unsigned short* __restrict__ Xs, unsigned short* __restrict__ Ys,
    float* __restrict__ pmax, float* __restrict__ psum,
    float* __restrict__ diag, unsigned* __restrict__ ctr,
    float* __restrict__ out) {
  __shared__ __align__(16) unsigned short As[8192];  // 16 KB
  __shared__ __align__(16) unsigned short Bs[8192];  // 16 KB
  __shared__ float redl[4], redc[4];
  const int blk = blockIdx.x;
  const int t = threadIdx.x;
  const int wave = t >> 6, lane = t & 63;

  // ---------------- Phase 0: transpose + bf16 cast into staged layout ------
  {
    if (blk == 0 && t == 0) { out[0] = 0.f; out[1] = 0.f; }
    const float* src;
    unsigned short* dst;
    int slab;
    if (blk < 256) { src = pred; dst = Xs; slab = blk; }
    else           { src = gt;   dst = Ys; slab = blk - 256; }
    const float* sb = src + slab * 4096;
    const int rb = slab >> 3, rowhi = slab & 7;
    #pragma unroll
    for (int half = 0; half < 2; ++half) {
      int c_ = half * 256 + t;               // chunk id within slab, 0..511
      int rowlo = c_ & 15;
      int quad  = (c_ >> 4) & 3;
      int kk    = (c_ >> 6) & 1;
      int s     = c_ >> 7;
      int k0 = s * 64 + kk * 32 + quad * 8;
      unsigned int packed[4];
      #pragma unroll
      for (int jj = 0; jj < 4; ++jj) {
        unsigned int lohi[2];
        #pragma unroll
        for (int e = 0; e < 2; ++e) {
          float f = sb[(k0 + jj * 2 + e) * 16 + rowlo];
          unsigned int u = __float_as_uint(f);
          lohi[e] = (u + 0x7FFFu + ((u >> 16) & 1u)) >> 16;  // RNE -> bf16
        }
        packed[jj] = lohi[0] | (lohi[1] << 16);
      }
      unsigned short* o = dst + rb * 32768 +
          (unsigned)(s * 1024 + kk * 512 + rowhi * 64 + quad * 16 + rowlo) * 8;
      uint4 v; v.x = packed[0]; v.y = packed[1]; v.z = packed[2]; v.w = packed[3];
      *reinterpret_cast<uint4*>(o) = v;
    }
  }
  grid_barrier(ctr + 0, 512);

  // ---------------- Phase 1: two 128x128 GEMM tiles + softmax partials -----
  const int rg = wave >> 1, cg_ = wave & 1;
  const int quad = lane >> 4, lc = lane & 15;
  for (int tile = blk; tile < 1024; tile += 512) {
    const int bR = tile >> 5, bC = tile & 31;
    const unsigned short* Ag = Xs + bR * 32768;
    const unsigned short* Bg = Ys + bC * 32768;

    floatx4 acc[4][4];
    const floatx4 zero = {0.f, 0.f, 0.f, 0.f};
    #pragma unroll
    for (int i = 0; i < 4; ++i)
      #pragma unroll
      for (int j = 0; j < 4; ++j) acc[i][j] = zero;

    __syncthreads();   // protect As/Bs against previous tile's readers
    for (int s = 0; s < 4; ++s) {
      #pragma unroll
      for (int it = 0; it < 4; ++it) {
        int chunk = it * 256 + t;      // lane-linear: 16B per thread
        __builtin_amdgcn_global_load_lds(AS1C(Ag + s * 8192 + chunk * 8),
                                         AS3(As + chunk * 8), 16, 0, 0);
        __builtin_amdgcn_global_load_lds(AS1C(Bg + s * 8192 + chunk * 8),
                                         AS3(Bs + chunk * 8), 16, 0, 0);
      }
      __syncthreads();
      #pragma unroll
      for (int kk = 0; kk < 2; ++kk) {
        bf16x8 a[4], b[4];
        #pragma unroll
        for (int fr = 0; fr < 4; ++fr)
          a[fr] = *reinterpret_cast<const bf16x8*>(
              As + (unsigned)(kk * 512 + (rg * 4 + fr) * 64 + lane) * 8);
        #pragma unroll
        for (int fc = 0; fc < 4; ++fc)
          b[fc] = *reinterpret_cast<const bf16x8*>(
              Bs + (unsigned)(kk * 512 + (cg_ * 4 + fc) * 64 + lane) * 8);
        #pragma unroll
        for (int fr = 0; fr < 4; ++fr)
          #pragma unroll
          for (int fc = 0; fc < 4; ++fc)
            acc[fr][fc] = __builtin_amdgcn_mfma_f32_16x16x32_bf16(
                a[fr], b[fc], acc[fr][fc], 0, 0, 0);
      }
      if (s < 3) __syncthreads();
    }

    // Diagonal: row_local = fr*16+quad*4+r, col_local = fc*16+lc.
    if (bR == bC && rg == cg_) {
      #pragma unroll
      for (int fr = 0; fr < 4; ++fr)
        #pragma unroll
        for (int r = 0; r < 4; ++r)
          if (lc == quad * 4 + r)
            diag[bR * 128 + rg * 64 + fr * 16 + lc] = acc[fr][fr][r];
    }

    // Per-row (max, sum-exp) partials over this wave's 64 cols.
    const int g = bC * 2 + cg_;
    #pragma unroll
    for (int fr = 0; fr < 4; ++fr) {
      #pragma unroll
      for (int r = 0; r < 4; ++r) {
        float v0 = acc[fr][0][r], v1 = acc[fr][1][r];
        float v2 = acc[fr][2][r], v3 = acc[fr][3][r];
        float m = fmaxf(fmaxf(v0, v1), fmaxf(v2, v3));
        #pragma unroll
        for (int sh = 1; sh < 16; sh <<= 1) m = fmaxf(m, __shfl_xor(m, sh, 64));
        float ss = __expf(v0 - m) + __expf(v1 - m) +
                   __expf(v2 - m) + __expf(v3 - m);
        #pragma unroll
        for (int sh = 1; sh < 16; sh <<= 1) ss += __shfl_xor(ss, sh, 64);
        if (lc == 0) {
          int grow = bR * 128 + rg * 64 + fr * 16 + quad * 4 + r;
          pmax[grow * 64 + g] = m;
          psum[grow * 64 + g] = ss;
        }
      }
    }
  }
  grid_barrier(ctr + 1, 512);

  // ---------------- Phase 2: combine partials, 8 rows/block ----------------
  {
    float lacc = 0.f, cacc = 0.f;
    #pragma unroll
    for (int r = 0; r < 2; ++r) {
      int row = blk * 8 + wave * 2 + r;
      float pm = pmax[row * 64 + lane];
      float ps = psum[row * 64 + lane];
      float M = pm;
      #pragma unroll
      for (int sh = 1; sh < 64; sh <<= 1) M = fmaxf(M, __shfl_xor(M, sh, 64));
      float S = ps * __expf(pm - M);
      #pragma unroll
      for (int sh = 1; sh < 64; sh <<= 1) S += __shfl_xor(S, sh, 64);
      float d = diag[row];
      lacc += logf(S) + M - d;
      cacc += (d == M) ? 1.f : 0.f;   // argmax value IS the row max
    }
    if (lane == 0) { redl[wave] = lacc; redc[wave] = cacc; }
    __syncthreads();
    if (t == 0) {
      atomicAdd(out + 0, (redl[0] + redl[1] + redl[2] + redl[3]) * (1.f / 4096.f));
      atomicAdd(out + 1, (redc[0] + redc[1] + redc[2] + redc[3]) * (100.f / 4096.f));
    }
  }
}

extern "C" void kernel_launch(void* const* d_in, const int* in_sizes, int n_in,
                              void* d_out, int out_size, void* d_ws, size_t ws_size,
                              hipStream_t stream) {
  const float* pred = (const float*)d_in[0];
  const float* gt   = (const float*)d_in[1];
  char* w = (char*)d_ws;
  unsigned short* Xs = (unsigned short*)(w + OFF_X);
  unsigned short* Ys = (unsigned short*)(w + OFF_Y);
  float* pmax  = (float*)(w + OFF_PMAX);
  float* psum  = (float*)(w + OFF_PSUM);
  float* diag  = (float*)(w + OFF_DIAG);
  unsigned* ctr = (unsigned*)(w + OFF_CTR);
  float* out   = (float*)d_out;

  // zero the barrier counters (ws is re-poisoned before every launch)
  hipMemsetAsync(ctr, 0, 2 * sizeof(unsigned), stream);
  dpc_fused<<<512, 256, 0, stream>>>(pred, gt, Xs, Ys, pmax, psum, diag,
                                     ctr, out);
}

// Round 6
// 240.652 us; speedup vs baseline: 1.1769x; 1.1769x over previous
//
#include <hip/hip_runtime.h>
#include <cstdint>

typedef __bf16 bf16x8 __attribute__((ext_vector_type(8)));
typedef float floatx4 __attribute__((ext_vector_type(4)));

// M = 4096 rows, C(K) = 256. GEMM block tile 128x128, K-slab 64.
// Staged layout: Xs[rb(32)][s(4)][kk(2)][rowhi(8)][quad(4)][rowlo(16)][8 bf16]
// = the exact LDS image for lane-linear global_load_lds staging and
// conflict-free lane-linear ds_read_b128 fragment reads.

#define OFF_X     (0u)
#define OFF_Y     (2u*1024*1024)
#define OFF_PMAX  (4u*1024*1024)   // [row(4096)][g(64)]
#define OFF_PSUM  (5u*1024*1024)
#define OFF_DIAG  (6u*1024*1024)
#define OFF_CTR   (6u*1024*1024 + 65536u)   // 32 u32 row-panel arrival ctrs

#define AS1C(p) ((const __attribute__((address_space(1))) void*)(const void*)(p))
#define AS3(p)  ((__attribute__((address_space(3))) void*)(void*)(p))

// Device-scope relaxed load: bypasses non-coherent per-XCD caches so the
// last-arriver combine reads partials written by blocks on other XCDs.
__device__ __forceinline__ float agent_load_f(const float* p) {
  return __hip_atomic_load(p, __ATOMIC_RELAXED, __HIP_MEMORY_SCOPE_AGENT);
}

// ---------------------------------------------------------------------------
// Node 1: transpose + bf16 cast into staged layout; zero d_out + panel ctrs.
// (kernel boundary to node 2 = free device-wide coherent barrier)
// ---------------------------------------------------------------------------
__global__ __launch_bounds__(256) void transpose_stage(
    const float* __restrict__ pred, const float* __restrict__ gt,
    unsigned short* __restrict__ Xs, unsigned short* __restrict__ Ys,
    unsigned* __restrict__ pctr, float* __restrict__ out) {
  int blk = blockIdx.x;
  if (blk == 0) {
    if (threadIdx.x < 32) pctr[threadIdx.x] = 0u;
    if (threadIdx.x < 2)  out[threadIdx.x] = 0.f;
  }
  const float* src;
  unsigned short* dst;
  int slab;
  if (blk < 256) { src = pred; dst = Xs; slab = blk; }
  else           { src = gt;   dst = Ys; slab = blk - 256; }
  const float* sb = src + slab * 4096;
  const int rb = slab >> 3, rowhi = slab & 7;
  const int t = threadIdx.x;
  #pragma unroll
  for (int half = 0; half < 2; ++half) {
    int c_ = half * 256 + t;                 // chunk id within slab, 0..511
    int rowlo = c_ & 15;
    int quad  = (c_ >> 4) & 3;
    int kk    = (c_ >> 6) & 1;
    int s     = c_ >> 7;
    int k0 = s * 64 + kk * 32 + quad * 8;
    unsigned int packed[4];
    #pragma unroll
    for (int jj = 0; jj < 4; ++jj) {
      unsigned int lohi[2];
      #pragma unroll
      for (int e = 0; e < 2; ++e) {
        float f = sb[(k0 + jj * 2 + e) * 16 + rowlo];
        unsigned int u = __float_as_uint(f);
        lohi[e] = (u + 0x7FFFu + ((u >> 16) & 1u)) >> 16;   // RNE -> bf16
      }
      packed[jj] = lohi[0] | (lohi[1] << 16);
    }
    unsigned short* o = dst + rb * 32768 +
        (unsigned)(s * 1024 + kk * 512 + rowhi * 64 + quad * 16 + rowlo) * 8;
    uint4 v; v.x = packed[0]; v.y = packed[1]; v.z = packed[2]; v.w = packed[3];
    *reinterpret_cast<uint4*>(o) = v;
  }
}

// ---------------------------------------------------------------------------
// Node 2: GEMM (1024 tiles of 128x128 over 512 blocks) + fused softmax
// partials + last-arriver per-panel combine. No spins: after a block stores
// a tile's partials it release-fences and takes a ticket on the row-panel's
// counter; ticket 31 (all 32 col-tiles done) acquire-fences and combines the
// panel's 128 rows, atomicAdd-ing into d_out.
// ---------------------------------------------------------------------------
__global__ __launch_bounds__(256, 2) void gemm_fused(
    const unsigned short* __restrict__ Xs, const unsigned short* __restrict__ Ys,
    float* __restrict__ pmax, float* __restrict__ psum,
    float* __restrict__ diag, unsigned* __restrict__ pctr,
    float* __restrict__ out) {
  __shared__ __align__(16) unsigned short As[8192];  // 16 KB
  __shared__ __align__(16) unsigned short Bs[8192];  // 16 KB
  __shared__ float redl[4], redc[4];
  __shared__ int s_last;
  const int blk = blockIdx.x;
  const int t = threadIdx.x;
  const int wave = t >> 6, lane = t & 63;
  const int rg = wave >> 1, cg_ = wave & 1;
  const int quad = lane >> 4, lc = lane & 15;

  for (int tile = blk; tile < 1024; tile += 512) {
    const int bR = tile >> 5, bC = tile & 31;
    const unsigned short* Ag = Xs + bR * 32768;
    const unsigned short* Bg = Ys + bC * 32768;

    floatx4 acc[4][4];
    const floatx4 zero = {0.f, 0.f, 0.f, 0.f};
    #pragma unroll
    for (int i = 0; i < 4; ++i)
      #pragma unroll
      for (int j = 0; j < 4; ++j) acc[i][j] = zero;

    __syncthreads();   // protect As/Bs against previous tile's readers
    for (int s = 0; s < 4; ++s) {
      #pragma unroll
      for (int it = 0; it < 4; ++it) {
        int chunk = it * 256 + t;      // lane-linear: 16B per thread
        __builtin_amdgcn_global_load_lds(AS1C(Ag + s * 8192 + chunk * 8),
                                         AS3(As + chunk * 8), 16, 0, 0);
        __builtin_amdgcn_global_load_lds(AS1C(Bg + s * 8192 + chunk * 8),
                                         AS3(Bs + chunk * 8), 16, 0, 0);
      }
      __syncthreads();
      #pragma unroll
      for (int kk = 0; kk < 2; ++kk) {
        bf16x8 a[4], b[4];
        #pragma unroll
        for (int fr = 0; fr < 4; ++fr)
          a[fr] = *reinterpret_cast<const bf16x8*>(
              As + (unsigned)(kk * 512 + (rg * 4 + fr) * 64 + lane) * 8);
        #pragma unroll
        for (int fc = 0; fc < 4; ++fc)
          b[fc] = *reinterpret_cast<const bf16x8*>(
              Bs + (unsigned)(kk * 512 + (cg_ * 4 + fc) * 64 + lane) * 8);
        #pragma unroll
        for (int fr = 0; fr < 4; ++fr)
          #pragma unroll
          for (int fc = 0; fc < 4; ++fc)
            acc[fr][fc] = __builtin_amdgcn_mfma_f32_16x16x32_bf16(
                a[fr], b[fc], acc[fr][fc], 0, 0, 0);
      }
      if (s < 3) __syncthreads();
    }

    // Diagonal: row_local = fr*16+quad*4+r, col_local = fc*16+lc.
    if (bR == bC && rg == cg_) {
      #pragma unroll
      for (int fr = 0; fr < 4; ++fr)
        #pragma unroll
        for (int r = 0; r < 4; ++r)
          if (lc == quad * 4 + r)
            diag[bR * 128 + rg * 64 + fr * 16 + lc] = acc[fr][fr][r];
    }

    // Per-row (max, sum-exp) partials over this wave's 64 cols.
    const int g = bC * 2 + cg_;
    #pragma unroll
    for (int fr = 0; fr < 4; ++fr) {
      #pragma unroll
      for (int r = 0; r < 4; ++r) {
        float v0 = acc[fr][0][r], v1 = acc[fr][1][r];
        float v2 = acc[fr][2][r], v3 = acc[fr][3][r];
        float m = fmaxf(fmaxf(v0, v1), fmaxf(v2, v3));
        #pragma unroll
        for (int sh = 1; sh < 16; sh <<= 1) m = fmaxf(m, __shfl_xor(m, sh, 64));
        float ss = __expf(v0 - m) + __expf(v1 - m) +
                   __expf(v2 - m) + __expf(v3 - m);
        #pragma unroll
        for (int sh = 1; sh < 16; sh <<= 1) ss += __shfl_xor(ss, sh, 64);
        if (lc == 0) {
          int grow = bR * 128 + rg * 64 + fr * 16 + quad * 4 + r;
          pmax[grow * 64 + g] = m;
          psum[grow * 64 + g] = ss;
        }
      }
    }

    // ---- arrival: release our stores, take a ticket on this row panel ----
    __threadfence();     // release (each thread fences its own stores)
    __syncthreads();     // all waves' fences done before the ticket
    if (t == 0) {
      unsigned tk = atomicAdd(&pctr[bR], 1u);
      s_last = (tk == 31u) ? 1 : 0;
    }
    __syncthreads();

    if (s_last) {
      __threadfence();   // acquire: don't read stale pre-arrival values
      // Combine panel bR's 128 rows; wave handles 32 rows, lane = col-group.
      float lacc = 0.f, cacc = 0.f;
      for (int i = 0; i < 32; ++i) {
        int row = bR * 128 + wave * 32 + i;
        float pm = agent_load_f(pmax + row * 64 + lane);
        float ps = agent_load_f(psum + row * 64 + lane);
        float M = pm;
        #pragma unroll
        for (int sh = 1; sh < 64; sh <<= 1) M = fmaxf(M, __shfl_xor(M, sh, 64));
        float S = ps * __expf(pm - M);
        #pragma unroll
        for (int sh = 1; sh < 64; sh <<= 1) S += __shfl_xor(S, sh, 64);
        float d = agent_load_f(diag + row);
        lacc += logf(S) + M - d;
        cacc += (d == M) ? 1.f : 0.f;   // argmax value IS the row max
      }
      if (lane == 0) { redl[wave] = lacc; redc[wave] = cacc; }
      __syncthreads();
      if (t == 0) {
        atomicAdd(out + 0,
                  (redl[0] + redl[1] + redl[2] + redl[3]) * (1.f / 4096.f));
        atomicAdd(out + 1,
                  (redc[0] + redc[1] + redc[2] + redc[3]) * (100.f / 4096.f));
      }
    }
  }
}

extern "C" void kernel_launch(void* const* d_in, const int* in_sizes, int n_in,
                              void* d_out, int out_size, void* d_ws, size_t ws_size,
                              hipStream_t stream) {
  const float* pred = (const float*)d_in[0];
  const float* gt   = (const float*)d_in[1];
  char* w = (char*)d_ws;
  unsigned short* Xs = (unsigned short*)(w + OFF_X);
  unsigned short* Ys = (unsigned short*)(w + OFF_Y);
  float* pmax  = (float*)(w + OFF_PMAX);
  float* psum  = (float*)(w + OFF_PSUM);
  float* diag  = (float*)(w + OFF_DIAG);
  unsigned* pctr = (unsigned*)(w + OFF_CTR);
  float* out   = (float*)d_out;

  transpose_stage<<<512, 256, 0, stream>>>(pred, gt, Xs, Ys, pctr, out);
  gemm_fused<<<512, 256, 0, stream>>>(Xs, Ys, pmax, psum, diag, pctr, out);
}

// Round 7
// 113.023 us; speedup vs baseline: 2.5059x; 2.1292x over previous
//
#include <hip/hip_runtime.h>
#include <cstdint>

typedef __bf16 bf16x8 __attribute__((ext_vector_type(8)));
typedef float floatx4 __attribute__((ext_vector_type(4)));

// M = 4096 rows, C(K) = 256. GEMM block tile 128x128, K-slab 64.
// Staged layout: Xs[rb(32)][s(4)][kk(2)][rowhi(8)][quad(4)][rowlo(16)][8 bf16]
// = the exact LDS image for lane-linear global_load_lds staging and
// conflict-free lane-linear ds_read_b128 fragment reads.

#define OFF_X     (0u)
#define OFF_Y     (2u*1024*1024)
#define OFF_PMAX  (4u*1024*1024)   // [row(4096)][g(64)]
#define OFF_PSUM  (5u*1024*1024)
#define OFF_DIAG  (6u*1024*1024)
#define OFF_CTR   (6u*1024*1024 + 65536u)   // 32 u32 row-panel arrival ctrs

#define AS1C(p) ((const __attribute__((address_space(1))) void*)(const void*)(p))
#define AS3(p)  ((__attribute__((address_space(3))) void*)(void*)(p))

// Coherent-point publication (NO cache-maintenance ops — the round-5/6
// lesson: buffer_wbl2 from device-scope fences costs ~100 µs grid-wide).
// Relaxed agent-scope atomics lower to sc0/sc1 loads/stores that bypass the
// non-coherent per-XCD L1/L2 and hit the device-coherent point directly.
__device__ __forceinline__ void pub_store_f(float* p, float v) {
  __hip_atomic_store(p, v, __ATOMIC_RELAXED, __HIP_MEMORY_SCOPE_AGENT);
}
__device__ __forceinline__ float pub_load_f(const float* p) {
  return __hip_atomic_load(p, __ATOMIC_RELAXED, __HIP_MEMORY_SCOPE_AGENT);
}

// ---------------------------------------------------------------------------
// Node 1: transpose + bf16 cast into staged layout; zero d_out + panel ctrs.
// Kernel boundary to node 2 = free coherent device-wide barrier.
// ---------------------------------------------------------------------------
__global__ __launch_bounds__(256) void transpose_stage(
    const float* __restrict__ pred, const float* __restrict__ gt,
    unsigned short* __restrict__ Xs, unsigned short* __restrict__ Ys,
    unsigned* __restrict__ pctr, float* __restrict__ out) {
  int blk = blockIdx.x;
  if (blk == 0) {
    if (threadIdx.x < 32) pctr[threadIdx.x] = 0u;
    if (threadIdx.x < 2)  out[threadIdx.x] = 0.f;
  }
  const float* src;
  unsigned short* dst;
  int slab;
  if (blk < 256) { src = pred; dst = Xs; slab = blk; }
  else           { src = gt;   dst = Ys; slab = blk - 256; }
  const float* sb = src + slab * 4096;
  const int rb = slab >> 3, rowhi = slab & 7;
  const int t = threadIdx.x;
  #pragma unroll
  for (int half = 0; half < 2; ++half) {
    int c_ = half * 256 + t;                 // chunk id within slab, 0..511
    int rowlo = c_ & 15;
    int quad  = (c_ >> 4) & 3;
    int kk    = (c_ >> 6) & 1;
    int s     = c_ >> 7;
    int k0 = s * 64 + kk * 32 + quad * 8;
    unsigned int packed[4];
    #pragma unroll
    for (int jj = 0; jj < 4; ++jj) {
      unsigned int lohi[2];
      #pragma unroll
      for (int e = 0; e < 2; ++e) {
        float f = sb[(k0 + jj * 2 + e) * 16 + rowlo];
        unsigned int u = __float_as_uint(f);
        lohi[e] = (u + 0x7FFFu + ((u >> 16) & 1u)) >> 16;   // RNE -> bf16
      }
      packed[jj] = lohi[0] | (lohi[1] << 16);
    }
    unsigned short* o = dst + rb * 32768 +
        (unsigned)(s * 1024 + kk * 512 + rowhi * 64 + quad * 16 + rowlo) * 8;
    uint4 v; v.x = packed[0]; v.y = packed[1]; v.z = packed[2]; v.w = packed[3];
    *reinterpret_cast<uint4*>(o) = v;
  }
}

// ---------------------------------------------------------------------------
// Node 2: 1024 tiles of 128x128 (1 per block) + fused softmax partials +
// last-arriver per-panel combine. No fences, no spins: partials published
// via write-through agent-scope stores; after s_waitcnt(0)+barrier a block
// takes a ticket on its row-panel counter; ticket 31 (all 32 col-tiles done)
// combines the panel's 128 rows and atomicAdds into d_out.
// ---------------------------------------------------------------------------
__global__ __launch_bounds__(256) void gemm_fused(
    const unsigned short* __restrict__ Xs, const unsigned short* __restrict__ Ys,
    float* __restrict__ pmax, float* __restrict__ psum,
    float* __restrict__ diag, unsigned* __restrict__ pctr,
    float* __restrict__ out) {
  __shared__ __align__(16) unsigned short As[8192];  // 16 KB
  __shared__ __align__(16) unsigned short Bs[8192];  // 16 KB
  __shared__ float redl[4], redc[4];
  __shared__ int s_last;
  const int t = threadIdx.x;
  const int wave = t >> 6, lane = t & 63;
  const int rg = wave >> 1, cg_ = wave & 1;
  const int quad = lane >> 4, lc = lane & 15;
  const int tile = blockIdx.x;
  const int bR = tile >> 5, bC = tile & 31;
  const unsigned short* Ag = Xs + bR * 32768;
  const unsigned short* Bg = Ys + bC * 32768;

  floatx4 acc[4][4];
  const floatx4 zero = {0.f, 0.f, 0.f, 0.f};
  #pragma unroll
  for (int i = 0; i < 4; ++i)
    #pragma unroll
    for (int j = 0; j < 4; ++j) acc[i][j] = zero;

  for (int s = 0; s < 4; ++s) {
    #pragma unroll
    for (int it = 0; it < 4; ++it) {
      int chunk = it * 256 + t;        // lane-linear: 16B per thread
      __builtin_amdgcn_global_load_lds(AS1C(Ag + s * 8192 + chunk * 8),
                                       AS3(As + chunk * 8), 16, 0, 0);
      __builtin_amdgcn_global_load_lds(AS1C(Bg + s * 8192 + chunk * 8),
                                       AS3(Bs + chunk * 8), 16, 0, 0);
    }
    __syncthreads();
    #pragma unroll
    for (int kk = 0; kk < 2; ++kk) {
      bf16x8 a[4], b[4];
      #pragma unroll
      for (int fr = 0; fr < 4; ++fr)
        a[fr] = *reinterpret_cast<const bf16x8*>(
            As + (unsigned)(kk * 512 + (rg * 4 + fr) * 64 + lane) * 8);
      #pragma unroll
      for (int fc = 0; fc < 4; ++fc)
        b[fc] = *reinterpret_cast<const bf16x8*>(
            Bs + (unsigned)(kk * 512 + (cg_ * 4 + fc) * 64 + lane) * 8);
      #pragma unroll
      for (int fr = 0; fr < 4; ++fr)
        #pragma unroll
        for (int fc = 0; fc < 4; ++fc)
          acc[fr][fc] = __builtin_amdgcn_mfma_f32_16x16x32_bf16(
              a[fr], b[fc], acc[fr][fc], 0, 0, 0);
    }
    if (s < 3) __syncthreads();
  }

  // Diagonal: row_local = fr*16+quad*4+r, col_local = fc*16+lc.
  if (bR == bC && rg == cg_) {
    #pragma unroll
    for (int fr = 0; fr < 4; ++fr)
      #pragma unroll
      for (int r = 0; r < 4; ++r)
        if (lc == quad * 4 + r)
          pub_store_f(diag + bR * 128 + rg * 64 + fr * 16 + lc, acc[fr][fr][r]);
  }

  // Per-row (max, sum-exp) partials over this wave's 64 cols.
  const int g = bC * 2 + cg_;
  #pragma unroll
  for (int fr = 0; fr < 4; ++fr) {
    #pragma unroll
    for (int r = 0; r < 4; ++r) {
      float v0 = acc[fr][0][r], v1 = acc[fr][1][r];
      float v2 = acc[fr][2][r], v3 = acc[fr][3][r];
      float m = fmaxf(fmaxf(v0, v1), fmaxf(v2, v3));
      #pragma unroll
      for (int sh = 1; sh < 16; sh <<= 1) m = fmaxf(m, __shfl_xor(m, sh, 64));
      float ss = __expf(v0 - m) + __expf(v1 - m) +
                 __expf(v2 - m) + __expf(v3 - m);
      #pragma unroll
      for (int sh = 1; sh < 16; sh <<= 1) ss += __shfl_xor(ss, sh, 64);
      if (lc == 0) {
        int grow = bR * 128 + rg * 64 + fr * 16 + quad * 4 + r;
        pub_store_f(pmax + grow * 64 + g, m);
        pub_store_f(psum + grow * 64 + g, ss);
      }
    }
  }

  // ---- arrival: retire write-through stores, then take a panel ticket ----
  __builtin_amdgcn_s_waitcnt(0);   // stores reached the coherent point
  __syncthreads();                 // all waves done publishing
  if (t == 0) {
    unsigned tk = __hip_atomic_fetch_add(&pctr[bR], 1u, __ATOMIC_RELAXED,
                                         __HIP_MEMORY_SCOPE_AGENT);
    s_last = (tk == 31u) ? 1 : 0;
  }
  __syncthreads();

  if (s_last) {
    // Combine panel bR's 128 rows; wave handles 32 rows, lane = col-group.
    float lacc = 0.f, cacc = 0.f;
    for (int i = 0; i < 32; ++i) {
      int row = bR * 128 + wave * 32 + i;
      float pm = pub_load_f(pmax + row * 64 + lane);
      float ps = pub_load_f(psum + row * 64 + lane);
      float M = pm;
      #pragma unroll
      for (int sh = 1; sh < 64; sh <<= 1) M = fmaxf(M, __shfl_xor(M, sh, 64));
      float S = ps * __expf(pm - M);
      #pragma unroll
      for (int sh = 1; sh < 64; sh <<= 1) S += __shfl_xor(S, sh, 64);
      float d = pub_load_f(diag + row);
      lacc += logf(S) + M - d;
      cacc += (d == M) ? 1.f : 0.f;   // argmax value IS the row max
    }
    if (lane == 0) { redl[wave] = lacc; redc[wave] = cacc; }
    __syncthreads();
    if (t == 0) {
      atomicAdd(out + 0,
                (redl[0] + redl[1] + redl[2] + redl[3]) * (1.f / 4096.f));
      atomicAdd(out + 1,
                (redc[0] + redc[1] + redc[2] + redc[3]) * (100.f / 4096.f));
    }
  }
}

extern "C" void kernel_launch(void* const* d_in, const int* in_sizes, int n_in,
                              void* d_out, int out_size, void* d_ws, size_t ws_size,
                              hipStream_t stream) {
  const float* pred = (const float*)d_in[0];
  const float* gt   = (const float*)d_in[1];
  char* w = (char*)d_ws;
  unsigned short* Xs = (unsigned short*)(w + OFF_X);
  unsigned short* Ys = (unsigned short*)(w + OFF_Y);
  float* pmax  = (float*)(w + OFF_PMAX);
  float* psum  = (float*)(w + OFF_PSUM);
  float* diag  = (float*)(w + OFF_DIAG);
  unsigned* pctr = (unsigned*)(w + OFF_CTR);
  float* out   = (float*)d_out;

  transpose_stage<<<512, 256, 0, stream>>>(pred, gt, Xs, Ys, pctr, out);
  gemm_fused<<<1024, 256, 0, stream>>>(Xs, Ys, pmax, psum, diag, pctr, out);
}